// Round 1
// baseline (2571.481 us; speedup 1.0000x reference)
//
#include <hip/hip_runtime.h>
#include <hip/hip_bf16.h>
#include <math.h>

#define D_MODEL 2048
#define D_FF    4096
#define NTOK    2048
#define NEXP    8
#define NPAIR   (NTOK*2)      // 4096 (token, expert) pairs, always exactly 2 per token
#define MAXTILES 48           // sum_e ceil(cnt_e/128) <= 4096/128 + 8 = 40

typedef __hip_bfloat16 bf16;
using frag_ab = __attribute__((ext_vector_type(8))) short;  // 8 bf16 (4 VGPRs)
using frag_cd = __attribute__((ext_vector_type(4))) float;  // 4 fp32 acc

__device__ __forceinline__ short f2bf_s(float f) {
  __hip_bfloat16 h = __float2bfloat16(f);
  union { __hip_bfloat16 b; short s; } u; u.b = h; return u.s;
}
__device__ __forceinline__ short4 f2bf4(const float4 v) {
  short4 r; r.x = f2bf_s(v.x); r.y = f2bf_s(v.y); r.z = f2bf_s(v.z); r.w = f2bf_s(v.w);
  return r;
}

// ---------------- K0: zero control arrays (ws is poisoned 0xAA every launch) --------
__global__ void k_zero(int* cnt, int* cur, float* psum) {
  int t = threadIdx.x;
  if (t < NEXP) { cnt[t] = 0; cur[t] = 0; psum[t] = 0.f; }
}

// ---------------- K1: routing: logits -> softmax -> top2 -> normalized weights -----
__global__ void k_route(const float* __restrict__ x, const float* __restrict__ Wr,
                        int* __restrict__ tki, float* __restrict__ tkw,
                        int* __restrict__ cnt, float* __restrict__ psum) {
  const int n = blockIdx.x;
  const int t = threadIdx.x;
  const float* xr = x + (size_t)n * D_MODEL;
  float acc[NEXP];
#pragma unroll
  for (int e = 0; e < NEXP; e++) acc[e] = 0.f;
  for (int d = t; d < D_MODEL; d += 256) {
    float xv = xr[d];
#pragma unroll
    for (int e = 0; e < NEXP; e++) acc[e] += xv * Wr[e * D_MODEL + d];
  }
  __shared__ float red[256 * NEXP];
#pragma unroll
  for (int e = 0; e < NEXP; e++) red[t * NEXP + e] = acc[e];
  __syncthreads();
  __shared__ float logit[NEXP];
  if (t < NEXP) {
    float s = 0.f;
    for (int i = 0; i < 256; i++) s += red[i * NEXP + t];
    logit[t] = s;
  }
  __syncthreads();
  if (t == 0) {
    float m = logit[0];
#pragma unroll
    for (int e = 1; e < NEXP; e++) m = fmaxf(m, logit[e]);
    float p[NEXP]; float s = 0.f;
#pragma unroll
    for (int e = 0; e < NEXP; e++) { p[e] = expf(logit[e] - m); s += p[e]; }
    float inv = 1.f / s;
#pragma unroll
    for (int e = 0; e < NEXP; e++) p[e] *= inv;
    // top-2, ties -> lower index (strict > preserves first occurrence, like lax.top_k)
    int i0 = 0;
#pragma unroll
    for (int e = 1; e < NEXP; e++) if (p[e] > p[i0]) i0 = e;
    int i1 = (i0 == 0) ? 1 : 0;
#pragma unroll
    for (int e = 0; e < NEXP; e++) if (e != i0 && e != i1 && p[e] > p[i1]) i1 = e;
    float wsum = p[i0] + p[i1];
    tki[n*2]   = i0;          tki[n*2+1] = i1;
    tkw[n*2]   = p[i0]/wsum;  tkw[n*2+1] = p[i1]/wsum;
    atomicAdd(&cnt[i0], 1);   atomicAdd(&cnt[i1], 1);
#pragma unroll
    for (int e = 0; e < NEXP; e++) atomicAdd(&psum[e], p[e]);
  }
}

// ---------------- K2: prefix scan, tile map, aux loss -------------------------------
__global__ void k_scan(const int* __restrict__ cnt, const float* __restrict__ psum,
                       int* __restrict__ off, int* __restrict__ te, int* __restrict__ tm,
                       float* __restrict__ aux_out) {
  if (threadIdx.x != 0) return;
  int o = 0;
  for (int e = 0; e < NEXP; e++) { off[e] = o; o += cnt[e]; }
  off[NEXP] = o;
  int nt = 0;
  for (int e = 0; e < NEXP; e++)
    for (int msv = 0; msv < cnt[e]; msv += 128) { te[nt] = e; tm[nt] = msv; nt++; }
  for (; nt < MAXTILES; nt++) { te[nt] = -1; tm[nt] = 0; }
  float aux = 0.f;
  for (int e = 0; e < NEXP; e++)
    aux += ((float)cnt[e] / (float)NPAIR) * (psum[e] / (float)NTOK);
  aux_out[0] = aux * 0.01f * (float)NEXP;
}

// ---------------- K3: assign ranks, build gather lists ------------------------------
__global__ void k_assign(const int* __restrict__ tki, const float* __restrict__ tkw,
                         const int* __restrict__ off, int* __restrict__ cur,
                         int* __restrict__ perm, float* __restrict__ pw,
                         int* __restrict__ posof) {
  int n = blockIdx.x * blockDim.x + threadIdx.x;
  if (n >= NTOK) return;
#pragma unroll
  for (int k = 0; k < 2; k++) {
    int e = tki[n*2+k];
    int r = atomicAdd(&cur[e], 1);
    int pos = off[e] + r;
    perm[pos] = n;
    pw[pos]   = tkw[n*2+k];
    posof[n*2+k] = pos;
  }
}

// ---------------- K4: fused GEMM1: H = silu(X W1) * (X W3), bf16 MFMA ---------------
// 128x128 tile, 256 thr = 4 waves in 2x2, each wave 64x64 via 4x4 of 16x16x32 MFMA.
__global__ __launch_bounds__(256) void k_gemm1(
    const float* __restrict__ x, const float* __restrict__ W1,
    const float* __restrict__ W3,
    const int* __restrict__ perm, const int* __restrict__ off,
    const int* __restrict__ tile_e, const int* __restrict__ tile_m,
    const int* __restrict__ cnt, bf16* __restrict__ H) {
  const int e = tile_e[blockIdx.y];
  if (e < 0) return;
  const int ms = tile_m[blockIdx.y];
  int mrows = cnt[e] - ms; if (mrows > 128) mrows = 128;
  const int f0 = blockIdx.x * 128;
  const int base = off[e] + ms;

  __shared__ __align__(16) bf16 As [128 * 40];  // [m][k], stride 40 bf16 (16B-aligned rows)
  __shared__ __align__(16) bf16 B1s[128 * 40];  // [f][k] (transposed on store)
  __shared__ __align__(16) bf16 B3s[128 * 40];

  const int t = threadIdx.x;
  const int lane = t & 63, wid = t >> 6;
  const int wm = wid & 1, wn = wid >> 1;
  const int lm = lane & 15, q = lane >> 4;

  frag_cd accg[4][4], accu[4][4];
#pragma unroll
  for (int i = 0; i < 4; i++)
#pragma unroll
    for (int j = 0; j < 4; j++) {
      accg[i][j] = {0.f,0.f,0.f,0.f};
      accu[i][j] = {0.f,0.f,0.f,0.f};
    }

  const float* W1e = W1 + (size_t)e * D_MODEL * D_FF;
  const float* W3e = W3 + (size_t)e * D_MODEL * D_FF;

  for (int k0 = 0; k0 < D_MODEL; k0 += 32) {
    // stage A: 128 rows x 32 k (gathered token rows, fp32 -> bf16)
#pragma unroll
    for (int i = 0; i < 4; i++) {
      int s = t + i * 256;            // 1024 float4 slots
      int row = s >> 3, kg = s & 7;
      float4 v = make_float4(0.f, 0.f, 0.f, 0.f);
      if (row < mrows) {
        int tok = perm[base + row];
        v = *(const float4*)(x + (size_t)tok * D_MODEL + k0 + kg * 4);
      }
      *(short4*)(&As[row * 40 + kg * 4]) = f2bf4(v);
    }
    // stage B1/B3: 32 k x 128 f, coalesced f-loads, LDS-transposed to [f][k]
#pragma unroll
    for (int i = 0; i < 4; i++) {
      int s = t + i * 256;
      int kr = s >> 5, fg = s & 31;
      const size_t gofs = (size_t)(k0 + kr) * D_FF + f0 + fg * 4;
      float4 v1 = *(const float4*)(W1e + gofs);
      float4 v3 = *(const float4*)(W3e + gofs);
      int fb = fg * 4;
      B1s[(fb+0)*40+kr] = __float2bfloat16(v1.x);
      B1s[(fb+1)*40+kr] = __float2bfloat16(v1.y);
      B1s[(fb+2)*40+kr] = __float2bfloat16(v1.z);
      B1s[(fb+3)*40+kr] = __float2bfloat16(v1.w);
      B3s[(fb+0)*40+kr] = __float2bfloat16(v3.x);
      B3s[(fb+1)*40+kr] = __float2bfloat16(v3.y);
      B3s[(fb+2)*40+kr] = __float2bfloat16(v3.z);
      B3s[(fb+3)*40+kr] = __float2bfloat16(v3.w);
    }
    __syncthreads();
    frag_ab a[4], b1[4], b3[4];
#pragma unroll
    for (int mf = 0; mf < 4; mf++)
      a[mf] = *(const frag_ab*)(&As[(wm*64 + mf*16 + lm) * 40 + q*8]);
#pragma unroll
    for (int nf = 0; nf < 4; nf++) {
      b1[nf] = *(const frag_ab*)(&B1s[(wn*64 + nf*16 + lm) * 40 + q*8]);
      b3[nf] = *(const frag_ab*)(&B3s[(wn*64 + nf*16 + lm) * 40 + q*8]);
    }
#pragma unroll
    for (int mf = 0; mf < 4; mf++)
#pragma unroll
      for (int nf = 0; nf < 4; nf++) {
        accg[mf][nf] = __builtin_amdgcn_mfma_f32_16x16x32_bf16(a[mf], b1[nf], accg[mf][nf], 0, 0, 0);
        accu[mf][nf] = __builtin_amdgcn_mfma_f32_16x16x32_bf16(a[mf], b3[nf], accu[mf][nf], 0, 0, 0);
      }
    __syncthreads();
  }
  // epilogue: H = silu(g) * u   (C/D layout: col=lane&15, row=(lane>>4)*4+reg)
#pragma unroll
  for (int mf = 0; mf < 4; mf++) {
#pragma unroll
    for (int r = 0; r < 4; r++) {
      int row = wm*64 + mf*16 + q*4 + r;
      if (row < mrows) {
        bf16* hrow = H + (size_t)(base + row) * D_FF;
#pragma unroll
        for (int nf = 0; nf < 4; nf++) {
          float g = accg[mf][nf][r];
          float u = accu[mf][nf][r];
          float h = g * u / (1.f + expf(-g));   // silu(g)*u
          hrow[f0 + wn*64 + nf*16 + lm] = __float2bfloat16(h);
        }
      }
    }
  }
}

// ---------------- K5: GEMM2: eo = w_pair * (H W2), bf16 MFMA ------------------------
__global__ __launch_bounds__(256) void k_gemm2(
    const bf16* __restrict__ H, const float* __restrict__ W2,
    const float* __restrict__ pw,
    const int* __restrict__ off, const int* __restrict__ tile_e,
    const int* __restrict__ tile_m, const int* __restrict__ cnt,
    float* __restrict__ eo) {
  const int e = tile_e[blockIdx.y];
  if (e < 0) return;
  const int ms = tile_m[blockIdx.y];
  int mrows = cnt[e] - ms; if (mrows > 128) mrows = 128;
  const int d0 = blockIdx.x * 128;
  const int base = off[e] + ms;

  __shared__ __align__(16) bf16 As[128 * 40];
  __shared__ __align__(16) bf16 Bs[128 * 40];

  const int t = threadIdx.x;
  const int lane = t & 63, wid = t >> 6;
  const int wm = wid & 1, wn = wid >> 1;
  const int lm = lane & 15, q = lane >> 4;

  frag_cd acc[4][4];
#pragma unroll
  for (int i = 0; i < 4; i++)
#pragma unroll
    for (int j = 0; j < 4; j++) acc[i][j] = {0.f,0.f,0.f,0.f};

  const float* W2e = W2 + (size_t)e * D_FF * D_MODEL;
  const short* Hs = (const short*)H;

  for (int k0 = 0; k0 < D_FF; k0 += 32) {
#pragma unroll
    for (int i = 0; i < 4; i++) {
      int s = t + i * 256;
      int row = s >> 3, kg = s & 7;
      short4 v = {0, 0, 0, 0};
      if (row < mrows)
        v = *(const short4*)(Hs + (size_t)(base + row) * D_FF + k0 + kg * 4);
      *(short4*)(&As[row * 40 + kg * 4]) = v;
    }
#pragma unroll
    for (int i = 0; i < 4; i++) {
      int s = t + i * 256;
      int kr = s >> 5, fg = s & 31;
      float4 v2 = *(const float4*)(W2e + (size_t)(k0 + kr) * D_MODEL + d0 + fg * 4);
      int fb = fg * 4;
      Bs[(fb+0)*40+kr] = __float2bfloat16(v2.x);
      Bs[(fb+1)*40+kr] = __float2bfloat16(v2.y);
      Bs[(fb+2)*40+kr] = __float2bfloat16(v2.z);
      Bs[(fb+3)*40+kr] = __float2bfloat16(v2.w);
    }
    __syncthreads();
    frag_ab a[4], b[4];
#pragma unroll
    for (int mf = 0; mf < 4; mf++)
      a[mf] = *(const frag_ab*)(&As[(wm*64 + mf*16 + lm) * 40 + q*8]);
#pragma unroll
    for (int nf = 0; nf < 4; nf++)
      b[nf] = *(const frag_ab*)(&Bs[(wn*64 + nf*16 + lm) * 40 + q*8]);
#pragma unroll
    for (int mf = 0; mf < 4; mf++)
#pragma unroll
      for (int nf = 0; nf < 4; nf++)
        acc[mf][nf] = __builtin_amdgcn_mfma_f32_16x16x32_bf16(a[mf], b[nf], acc[mf][nf], 0, 0, 0);
    __syncthreads();
  }
#pragma unroll
  for (int mf = 0; mf < 4; mf++) {
#pragma unroll
    for (int r = 0; r < 4; r++) {
      int row = wm*64 + mf*16 + q*4 + r;
      if (row < mrows) {
        float w = pw[base + row];
        float* orow = eo + (size_t)(base + row) * D_MODEL;
#pragma unroll
        for (int nf = 0; nf < 4; nf++)
          orow[d0 + wn*64 + nf*16 + lm] = w * acc[mf][nf][r];
      }
    }
  }
}

// ---------------- K6: combine the two expert outputs per token ----------------------
__global__ void k_combine(const float* __restrict__ eo, const int* __restrict__ posof,
                          float* __restrict__ out) {
  int idx = blockIdx.x * 256 + threadIdx.x;   // over NTOK * (D_MODEL/4)
  int n = idx >> 9;                           // D_MODEL/4 = 512
  int c = (idx & 511) * 4;
  int p0 = posof[n*2], p1 = posof[n*2+1];
  const float4 a = *(const float4*)(eo + (size_t)p0 * D_MODEL + c);
  const float4 b = *(const float4*)(eo + (size_t)p1 * D_MODEL + c);
  float4 r;
  r.x = a.x + b.x; r.y = a.y + b.y; r.z = a.z + b.z; r.w = a.w + b.w;
  *(float4*)(out + (size_t)n * D_MODEL + c) = r;
}

extern "C" void kernel_launch(void* const* d_in, const int* in_sizes, int n_in,
                              void* d_out, int out_size, void* d_ws, size_t ws_size,
                              hipStream_t stream) {
  const float* x  = (const float*)d_in[0];
  const float* Wr = (const float*)d_in[1];
  const float* W1 = (const float*)d_in[2];
  const float* W3 = (const float*)d_in[3];
  const float* W2 = (const float*)d_in[4];
  float* out = (float*)d_out;

  char* ws = (char*)d_ws;
  bf16*  H    = (bf16*)(ws);                     // 4096*4096*2  = 33.55 MB
  float* eo   = (float*)(ws + 33554432);         // 4096*2048*4  = 33.55 MB
  char*  ib   = ws + 67108864;
  int*   perm  = (int*)(ib);
  float* pw    = (float*)(ib + 16384);
  int*   posof = (int*)(ib + 32768);
  int*   tki   = (int*)(ib + 49152);
  float* tkw   = (float*)(ib + 65536);
  int*   cnt   = (int*)(ib + 81920);
  int*   cur   = (int*)(ib + 82048);
  int*   off   = (int*)(ib + 82176);
  int*   te    = (int*)(ib + 82432);
  int*   tm    = (int*)(ib + 82688);
  float* psum  = (float*)(ib + 82944);

  k_zero<<<1, 64, 0, stream>>>(cnt, cur, psum);
  k_route<<<NTOK, 256, 0, stream>>>(x, Wr, tki, tkw, cnt, psum);
  k_scan<<<1, 1, 0, stream>>>(cnt, psum, off, te, tm, out + (size_t)NTOK * D_MODEL);
  k_assign<<<NTOK/256, 256, 0, stream>>>(tki, tkw, off, cur, perm, pw, posof);
  k_gemm1<<<dim3(D_FF/128, MAXTILES), 256, 0, stream>>>(x, W1, W3, perm, off, te, tm, cnt, H);
  k_gemm2<<<dim3(D_MODEL/128, MAXTILES), 256, 0, stream>>>(H, W2, pw, off, te, tm, cnt, eo);
  k_combine<<<(NTOK*(D_MODEL/4))/256, 256, 0, stream>>>(eo, posof, out);
}

// Round 2
// 1765.324 us; speedup vs baseline: 1.4567x; 1.4567x over previous
//
#include <hip/hip_runtime.h>
#include <hip/hip_bf16.h>
#include <math.h>

#define D_MODEL 2048
#define D_FF    4096
#define NTOK    2048
#define NEXP    8
#define NPAIR   (NTOK*2)      // 4096 (token, expert) pairs, always exactly 2 per token
#define MAXTILES 48           // sum_e ceil(cnt_e/128) <= 4096/128 + 8 = 40

typedef __hip_bfloat16 bf16;
using frag_ab = __attribute__((ext_vector_type(8))) short;  // 8 bf16 (4 VGPRs)
using frag_cd = __attribute__((ext_vector_type(4))) float;  // 4 fp32 acc

__device__ __forceinline__ short f2bf_s(float f) {
  __hip_bfloat16 h = __float2bfloat16(f);
  union { __hip_bfloat16 b; short s; } u; u.b = h; return u.s;
}
__device__ __forceinline__ short4 f2bf4(const float4 v) {
  short4 r; r.x = f2bf_s(v.x); r.y = f2bf_s(v.y); r.z = f2bf_s(v.z); r.w = f2bf_s(v.w);
  return r;
}

// ---------------- K0: zero control arrays (ws is poisoned 0xAA every launch) --------
__global__ void k_zero(int* cnt, int* cur, float* psum) {
  int t = threadIdx.x;
  if (t < NEXP) { cnt[t] = 0; cur[t] = 0; psum[t] = 0.f; }
}

// ---------------- K1: routing: logits -> softmax -> top2 -> normalized weights -----
__global__ void k_route(const float* __restrict__ x, const float* __restrict__ Wr,
                        int* __restrict__ tki, float* __restrict__ tkw,
                        int* __restrict__ cnt, float* __restrict__ psum) {
  const int n = blockIdx.x;
  const int t = threadIdx.x;
  const float* xr = x + (size_t)n * D_MODEL;
  float acc[NEXP];
#pragma unroll
  for (int e = 0; e < NEXP; e++) acc[e] = 0.f;
  for (int d = t; d < D_MODEL; d += 256) {
    float xv = xr[d];
#pragma unroll
    for (int e = 0; e < NEXP; e++) acc[e] += xv * Wr[e * D_MODEL + d];
  }
  __shared__ float red[256 * NEXP];
#pragma unroll
  for (int e = 0; e < NEXP; e++) red[t * NEXP + e] = acc[e];
  __syncthreads();
  __shared__ float logit[NEXP];
  if (t < NEXP) {
    float s = 0.f;
    for (int i = 0; i < 256; i++) s += red[i * NEXP + t];
    logit[t] = s;
  }
  __syncthreads();
  if (t == 0) {
    float m = logit[0];
#pragma unroll
    for (int e = 1; e < NEXP; e++) m = fmaxf(m, logit[e]);
    float p[NEXP]; float s = 0.f;
#pragma unroll
    for (int e = 0; e < NEXP; e++) { p[e] = expf(logit[e] - m); s += p[e]; }
    float inv = 1.f / s;
#pragma unroll
    for (int e = 0; e < NEXP; e++) p[e] *= inv;
    // top-2, ties -> lower index (strict > preserves first occurrence, like lax.top_k)
    int i0 = 0;
#pragma unroll
    for (int e = 1; e < NEXP; e++) if (p[e] > p[i0]) i0 = e;
    int i1 = (i0 == 0) ? 1 : 0;
#pragma unroll
    for (int e = 0; e < NEXP; e++) if (e != i0 && e != i1 && p[e] > p[i1]) i1 = e;
    float wsum = p[i0] + p[i1];
    tki[n*2]   = i0;          tki[n*2+1] = i1;
    tkw[n*2]   = p[i0]/wsum;  tkw[n*2+1] = p[i1]/wsum;
    atomicAdd(&cnt[i0], 1);   atomicAdd(&cnt[i1], 1);
#pragma unroll
    for (int e = 0; e < NEXP; e++) atomicAdd(&psum[e], p[e]);
  }
}

// ---------------- K2: prefix scan, tile map, aux loss -------------------------------
__global__ void k_scan(const int* __restrict__ cnt, const float* __restrict__ psum,
                       int* __restrict__ off, int* __restrict__ te, int* __restrict__ tm,
                       float* __restrict__ aux_out) {
  if (threadIdx.x != 0) return;
  int o = 0;
  for (int e = 0; e < NEXP; e++) { off[e] = o; o += cnt[e]; }
  off[NEXP] = o;
  int nt = 0;
  for (int e = 0; e < NEXP; e++)
    for (int msv = 0; msv < cnt[e]; msv += 128) { te[nt] = e; tm[nt] = msv; nt++; }
  for (; nt < MAXTILES; nt++) { te[nt] = -1; tm[nt] = 0; }
  float aux = 0.f;
  for (int e = 0; e < NEXP; e++)
    aux += ((float)cnt[e] / (float)NPAIR) * (psum[e] / (float)NTOK);
  aux_out[0] = aux * 0.01f * (float)NEXP;
}

// ---------------- K3: assign ranks, build gather lists ------------------------------
__global__ void k_assign(const int* __restrict__ tki, const float* __restrict__ tkw,
                         const int* __restrict__ off, int* __restrict__ cur,
                         int* __restrict__ perm, float* __restrict__ pw,
                         int* __restrict__ posof) {
  int n = blockIdx.x * blockDim.x + threadIdx.x;
  if (n >= NTOK) return;
#pragma unroll
  for (int k = 0; k < 2; k++) {
    int e = tki[n*2+k];
    int r = atomicAdd(&cur[e], 1);
    int pos = off[e] + r;
    perm[pos] = n;
    pw[pos]   = tkw[n*2+k];
    posof[n*2+k] = pos;
  }
}

// ---------------- K4: fused GEMM1: H = silu(X W1) * (X W3), bf16 MFMA ---------------
// 128x128 tile, 256 thr = 4 waves in 2x2, each wave 64x64 via 4x4 of 16x16x32 MFMA.
// B staged via k-run gather: 8 coalesced dword loads along k -> bf16x8 -> ds_write_b128
// into [f][k] stride-40 rows (start banks cycle all 32 banks, zero excess conflict).
__global__ __launch_bounds__(256) void k_gemm1(
    const float* __restrict__ x, const float* __restrict__ W1,
    const float* __restrict__ W3,
    const int* __restrict__ perm, const int* __restrict__ off,
    const int* __restrict__ tile_e, const int* __restrict__ tile_m,
    const int* __restrict__ cnt, bf16* __restrict__ H) {
  const int e = tile_e[blockIdx.y];
  if (e < 0) return;
  const int ms = tile_m[blockIdx.y];
  int mrows = cnt[e] - ms; if (mrows > 128) mrows = 128;
  const int f0 = blockIdx.x * 128;
  const int base = off[e] + ms;

  __shared__ __align__(16) bf16 As [128 * 40];  // [m][k], stride 40 bf16
  __shared__ __align__(16) bf16 B1s[128 * 40];  // [f][k]
  __shared__ __align__(16) bf16 B3s[128 * 40];
  __shared__ int permS[128];

  const int t = threadIdx.x;
  const int lane = t & 63, wid = t >> 6;
  const int wm = wid & 1, wn = wid >> 1;
  const int lm = lane & 15, q = lane >> 4;

  if (t < 128) permS[t] = (t < mrows) ? perm[base + t] : 0;

  frag_cd accg[4][4], accu[4][4];
#pragma unroll
  for (int i = 0; i < 4; i++)
#pragma unroll
    for (int j = 0; j < 4; j++) {
      accg[i][j] = {0.f,0.f,0.f,0.f};
      accu[i][j] = {0.f,0.f,0.f,0.f};
    }

  const float* W1e = W1 + (size_t)e * D_MODEL * D_FF;
  const float* W3e = W3 + (size_t)e * D_MODEL * D_FF;
  __syncthreads();

  for (int k0 = 0; k0 < D_MODEL; k0 += 32) {
    // stage A: 128 rows x 32 k (gathered token rows, fp32 -> bf16), 8B LDS writes
#pragma unroll
    for (int i = 0; i < 4; i++) {
      int s = t + i * 256;            // 1024 float4 slots
      int row = s >> 3, kg = s & 7;
      float4 v = make_float4(0.f, 0.f, 0.f, 0.f);
      if (row < mrows) {
        int tok = permS[row];
        v = *(const float4*)(x + (size_t)tok * D_MODEL + k0 + kg * 4);
      }
      *(short4*)(&As[row * 40 + kg * 4]) = f2bf4(v);
    }
    // stage B1/B3: k-run gather, one ds_write_b128 per run, conflict-free
#pragma unroll
    for (int i = 0; i < 2; i++) {
      int s = t + i * 256;            // 512 runs of 8 k
      int f = s & 127, kg = s >> 7;   // kg in 0..3
      const float* g1 = W1e + (size_t)(k0 + kg * 8) * D_FF + f0 + f;
      const float* g3 = W3e + (size_t)(k0 + kg * 8) * D_FF + f0 + f;
      short r1[8], r3[8];
#pragma unroll
      for (int j = 0; j < 8; j++) r1[j] = f2bf_s(g1[(size_t)j * D_FF]);
#pragma unroll
      for (int j = 0; j < 8; j++) r3[j] = f2bf_s(g3[(size_t)j * D_FF]);
      *(frag_ab*)(&B1s[f * 40 + kg * 8]) = *(const frag_ab*)r1;
      *(frag_ab*)(&B3s[f * 40 + kg * 8]) = *(const frag_ab*)r3;
    }
    __syncthreads();
    frag_ab a[4], b1[4], b3[4];
#pragma unroll
    for (int mf = 0; mf < 4; mf++)
      a[mf] = *(const frag_ab*)(&As[(wm*64 + mf*16 + lm) * 40 + q*8]);
#pragma unroll
    for (int nf = 0; nf < 4; nf++) {
      b1[nf] = *(const frag_ab*)(&B1s[(wn*64 + nf*16 + lm) * 40 + q*8]);
      b3[nf] = *(const frag_ab*)(&B3s[(wn*64 + nf*16 + lm) * 40 + q*8]);
    }
#pragma unroll
    for (int mf = 0; mf < 4; mf++)
#pragma unroll
      for (int nf = 0; nf < 4; nf++) {
        accg[mf][nf] = __builtin_amdgcn_mfma_f32_16x16x32_bf16(a[mf], b1[nf], accg[mf][nf], 0, 0, 0);
        accu[mf][nf] = __builtin_amdgcn_mfma_f32_16x16x32_bf16(a[mf], b3[nf], accu[mf][nf], 0, 0, 0);
      }
    __syncthreads();
  }
  // epilogue: H = silu(g) * u   (C/D layout: col=lane&15, row=(lane>>4)*4+reg)
#pragma unroll
  for (int mf = 0; mf < 4; mf++) {
#pragma unroll
    for (int r = 0; r < 4; r++) {
      int row = wm*64 + mf*16 + q*4 + r;
      if (row < mrows) {
        bf16* hrow = H + (size_t)(base + row) * D_FF;
#pragma unroll
        for (int nf = 0; nf < 4; nf++) {
          float g = accg[mf][nf][r];
          float u = accu[mf][nf][r];
          float h = g * u / (1.f + expf(-g));   // silu(g)*u
          hrow[f0 + wn*64 + nf*16 + lm] = __float2bfloat16(h);
        }
      }
    }
  }
}

// ---------------- K5: GEMM2: eo = w_pair * (H W2), bf16 MFMA ------------------------
__global__ __launch_bounds__(256) void k_gemm2(
    const bf16* __restrict__ H, const float* __restrict__ W2,
    const float* __restrict__ pw,
    const int* __restrict__ off, const int* __restrict__ tile_e,
    const int* __restrict__ tile_m, const int* __restrict__ cnt,
    float* __restrict__ eo) {
  const int e = tile_e[blockIdx.y];
  if (e < 0) return;
  const int ms = tile_m[blockIdx.y];
  int mrows = cnt[e] - ms; if (mrows > 128) mrows = 128;
  const int d0 = blockIdx.x * 128;
  const int base = off[e] + ms;

  __shared__ __align__(16) bf16 As[128 * 40];
  __shared__ __align__(16) bf16 Bs[128 * 40];

  const int t = threadIdx.x;
  const int lane = t & 63, wid = t >> 6;
  const int wm = wid & 1, wn = wid >> 1;
  const int lm = lane & 15, q = lane >> 4;

  frag_cd acc[4][4];
#pragma unroll
  for (int i = 0; i < 4; i++)
#pragma unroll
    for (int j = 0; j < 4; j++) acc[i][j] = {0.f,0.f,0.f,0.f};

  const float* W2e = W2 + (size_t)e * D_FF * D_MODEL;
  const short* Hs = (const short*)H;

  for (int k0 = 0; k0 < D_FF; k0 += 32) {
    // stage A (H rows, already bf16): 16B global loads -> 16B LDS writes
#pragma unroll
    for (int i = 0; i < 2; i++) {
      int s = t + i * 256;           // 512 slots of 8 bf16
      int row = s >> 2, kg = s & 3;
      frag_ab v = {0,0,0,0,0,0,0,0};
      if (row < mrows)
        v = *(const frag_ab*)(Hs + (size_t)(base + row) * D_FF + k0 + kg * 8);
      *(frag_ab*)(&As[row * 40 + kg * 8]) = v;
    }
    // stage B (W2): k-run gather, conflict-free
#pragma unroll
    for (int i = 0; i < 2; i++) {
      int s = t + i * 256;
      int dd = s & 127, kg = s >> 7;
      const float* g2 = W2e + (size_t)(k0 + kg * 8) * D_MODEL + d0 + dd;
      short r2[8];
#pragma unroll
      for (int j = 0; j < 8; j++) r2[j] = f2bf_s(g2[(size_t)j * D_MODEL]);
      *(frag_ab*)(&Bs[dd * 40 + kg * 8]) = *(const frag_ab*)r2;
    }
    __syncthreads();
    frag_ab a[4], b[4];
#pragma unroll
    for (int mf = 0; mf < 4; mf++)
      a[mf] = *(const frag_ab*)(&As[(wm*64 + mf*16 + lm) * 40 + q*8]);
#pragma unroll
    for (int nf = 0; nf < 4; nf++)
      b[nf] = *(const frag_ab*)(&Bs[(wn*64 + nf*16 + lm) * 40 + q*8]);
#pragma unroll
    for (int mf = 0; mf < 4; mf++)
#pragma unroll
      for (int nf = 0; nf < 4; nf++)
        acc[mf][nf] = __builtin_amdgcn_mfma_f32_16x16x32_bf16(a[mf], b[nf], acc[mf][nf], 0, 0, 0);
    __syncthreads();
  }
#pragma unroll
  for (int mf = 0; mf < 4; mf++) {
#pragma unroll
    for (int r = 0; r < 4; r++) {
      int row = wm*64 + mf*16 + q*4 + r;
      if (row < mrows) {
        float w = pw[base + row];
        float* orow = eo + (size_t)(base + row) * D_MODEL;
#pragma unroll
        for (int nf = 0; nf < 4; nf++)
          orow[d0 + wn*64 + nf*16 + lm] = w * acc[mf][nf][r];
      }
    }
  }
}

// ---------------- K6: combine the two expert outputs per token ----------------------
__global__ void k_combine(const float* __restrict__ eo, const int* __restrict__ posof,
                          float* __restrict__ out) {
  int idx = blockIdx.x * 256 + threadIdx.x;   // over NTOK * (D_MODEL/4)
  int n = idx >> 9;                           // D_MODEL/4 = 512
  int c = (idx & 511) * 4;
  int p0 = posof[n*2], p1 = posof[n*2+1];
  const float4 a = *(const float4*)(eo + (size_t)p0 * D_MODEL + c);
  const float4 b = *(const float4*)(eo + (size_t)p1 * D_MODEL + c);
  float4 r;
  r.x = a.x + b.x; r.y = a.y + b.y; r.z = a.z + b.z; r.w = a.w + b.w;
  *(float4*)(out + (size_t)n * D_MODEL + c) = r;
}

extern "C" void kernel_launch(void* const* d_in, const int* in_sizes, int n_in,
                              void* d_out, int out_size, void* d_ws, size_t ws_size,
                              hipStream_t stream) {
  const float* x  = (const float*)d_in[0];
  const float* Wr = (const float*)d_in[1];
  const float* W1 = (const float*)d_in[2];
  const float* W3 = (const float*)d_in[3];
  const float* W2 = (const float*)d_in[4];
  float* out = (float*)d_out;

  char* ws = (char*)d_ws;
  bf16*  H    = (bf16*)(ws);                     // 4096*4096*2  = 33.55 MB
  float* eo   = (float*)(ws + 33554432);         // 4096*2048*4  = 33.55 MB
  char*  ib   = ws + 67108864;
  int*   perm  = (int*)(ib);
  float* pw    = (float*)(ib + 16384);
  int*   posof = (int*)(ib + 32768);
  int*   tki   = (int*)(ib + 49152);
  float* tkw   = (float*)(ib + 65536);
  int*   cnt   = (int*)(ib + 81920);
  int*   cur   = (int*)(ib + 82048);
  int*   off   = (int*)(ib + 82176);
  int*   te    = (int*)(ib + 82432);
  int*   tm    = (int*)(ib + 82688);
  float* psum  = (float*)(ib + 82944);

  k_zero<<<1, 64, 0, stream>>>(cnt, cur, psum);
  k_route<<<NTOK, 256, 0, stream>>>(x, Wr, tki, tkw, cnt, psum);
  k_scan<<<1, 1, 0, stream>>>(cnt, psum, off, te, tm, out + (size_t)NTOK * D_MODEL);
  k_assign<<<NTOK/256, 256, 0, stream>>>(tki, tkw, off, cur, perm, pw, posof);
  k_gemm1<<<dim3(D_FF/128, MAXTILES), 256, 0, stream>>>(x, W1, W3, perm, off, te, tm, cnt, H);
  k_gemm2<<<dim3(D_MODEL/128, MAXTILES), 256, 0, stream>>>(H, W2, pw, off, te, tm, cnt, eo);
  k_combine<<<(NTOK*(D_MODEL/4))/256, 256, 0, stream>>>(eo, posof, out);
}